// Round 3
// baseline (544.978 us; speedup 1.0000x reference)
//
#include <hip/hip_runtime.h>
#include <hip/hip_bf16.h>

typedef unsigned short u16;
typedef unsigned int u32;
typedef short s16x8 __attribute__((ext_vector_type(8)));
typedef float f32x4 __attribute__((ext_vector_type(4)));

#define NB 8
#define NT 2048
#define NC 512
#define NH 512

__device__ __forceinline__ u16 f2bf(float f) {
  unsigned u = __float_as_uint(f);
  u += 0x7FFFu + ((u >> 16) & 1u);   // round-to-nearest-even
  return (u16)(u >> 16);
}

// ---------------- K0: W [C][H] fp32 -> WT [H][C] bf16 ----------------
__global__ __launch_bounds__(256) void wt_kernel(const float* __restrict__ W,
                                                 u16* __restrict__ WT) {
  __shared__ float tile[32][33];
  const int x = threadIdx.x & 31;
  const int y = threadIdx.x >> 5;
  const int k0 = blockIdx.x * 32, h0 = blockIdx.y * 32;
#pragma unroll
  for (int p = 0; p < 4; ++p)
    tile[y + 8 * p][x] = W[(size_t)(k0 + y + 8 * p) * NH + h0 + x];
  __syncthreads();
#pragma unroll
  for (int p = 0; p < 4; ++p)
    WT[(size_t)(h0 + y + 8 * p) * NC + k0 + x] = f2bf(tile[x][y + 8 * p]);
}

// ---------------- K1: Y = X @ W + b   (X fp32 [M][512], WT bf16 [N][K], Y bf16) ----
__global__ __launch_bounds__(256) void proj_kernel(const float* __restrict__ X,
                                                   const u16* __restrict__ WT,
                                                   const float* __restrict__ bias,
                                                   u16* __restrict__ Y) {
  __shared__ __align__(16) u16 Asub[128 * 40];
  __shared__ __align__(16) u16 Bsub[128 * 40];
  const int t = threadIdx.x;
  const int lane = t & 63;
  const int w = t >> 6;
  const int l16 = lane & 15;
  const int ko8 = (lane >> 4) * 8;
  const int m0 = blockIdx.y * 128;
  const int n0 = blockIdx.x * 128;
  const int wr = (w >> 1) * 64, wc = (w & 1) * 64;
  f32x4 acc[4][4] = {};

  for (int kt = 0; kt < 16; ++kt) {
    const int k0 = kt * 32;
#pragma unroll
    for (int p = 0; p < 4; ++p) {
      int c = t + 256 * p;
      int r = c >> 3, cc = (c & 7) * 4;
      const float4 v = *(const float4*)&X[(size_t)(m0 + r) * NC + k0 + cc];
      ushort4 bb;
      bb.x = f2bf(v.x); bb.y = f2bf(v.y); bb.z = f2bf(v.z); bb.w = f2bf(v.w);
      *(ushort4*)&Asub[r * 40 + cc] = bb;
    }
#pragma unroll
    for (int p = 0; p < 2; ++p) {
      int c = t + 256 * p;
      int r = c >> 2, cc = (c & 3) * 8;
      *(int4*)&Bsub[r * 40 + cc] = *(const int4*)&WT[(size_t)(n0 + r) * NC + k0 + cc];
    }
    __syncthreads();
    s16x8 af[4], bf[4];
#pragma unroll
    for (int i = 0; i < 4; ++i)
      af[i] = *(const s16x8*)&Asub[(wr + i * 16 + l16) * 40 + ko8];
#pragma unroll
    for (int j = 0; j < 4; ++j)
      bf[j] = *(const s16x8*)&Bsub[(wc + j * 16 + l16) * 40 + ko8];
#pragma unroll
    for (int i = 0; i < 4; ++i)
#pragma unroll
      for (int j = 0; j < 4; ++j)
        acc[i][j] = __builtin_amdgcn_mfma_f32_16x16x32_bf16(af[i], bf[j], acc[i][j], 0, 0, 0);
    __syncthreads();
  }
  const int rg = (lane >> 4) * 4;
#pragma unroll
  for (int i = 0; i < 4; ++i)
#pragma unroll
    for (int j = 0; j < 4; ++j) {
      const int col = n0 + wc + j * 16 + l16;
      const float bcol = bias[col];
#pragma unroll
      for (int jj = 0; jj < 4; ++jj) {
        const int row = m0 + wr + i * 16 + rg + jj;
        Y[(size_t)row * NH + col] = f2bf(acc[i][j][jj] + bcol);
      }
    }
}

// ---------------- K2: Vp [B][T][H] bf16 -> VpT [B][H][T] bf16 ----------------
__global__ __launch_bounds__(256) void vt_kernel(const u16* __restrict__ Vp,
                                                 u16* __restrict__ VpT) {
  __shared__ u16 tile[32][33];
  const int x = threadIdx.x & 31;
  const int y = threadIdx.x >> 5;
  const int t0 = blockIdx.x * 32, h0 = blockIdx.y * 32, b = blockIdx.z;
  const u16* src = Vp + (size_t)b * NT * NH;
  u16* dst = VpT + (size_t)b * NH * NT;
#pragma unroll
  for (int p = 0; p < 4; ++p)
    tile[y + 8 * p][x] = src[(size_t)(t0 + y + 8 * p) * NH + h0 + x];
  __syncthreads();
#pragma unroll
  for (int p = 0; p < 4; ++p)
    dst[(size_t)(h0 + y + 8 * p) * NT + t0 + x] = tile[x][y + 8 * p];
}

// ---------------- K3: flash attention (wave-local softmax, swapped operands) ----
// grid (NB=8, 32): flat id = batch + 8*qchunk -> round-robin puts batch b on XCD b.
// block = 256 threads (4 waves). Each wave owns 16 q rows end-to-end (QB=64/block).
// Per iter: stage K[32][512] + V^T[512][32] (double-buffered, reg-staged
// issue-early/write-late), 1 barrier.
// S^T = mfma(K, Q^T): lane holds col q=l16, rows kv=(g*4+j | 16+g*4+j).
// Softmax fully in-register (per-lane q). P^T -> B-frag via 8 shuffles.
// O^T = mfma(V^T, P^T): lane holds col q=l16, rows h -> float4 stores.
__global__ __launch_bounds__(256, 1) void flash_kernel(const u16* __restrict__ Qp,
                                                       const u16* __restrict__ Kp,
                                                       const u16* __restrict__ VpT,
                                                       float* __restrict__ out) {
  __shared__ __align__(16) u16 Klds[2][32 * 520];   // [kv][d], pad 8
  __shared__ __align__(16) u16 Vlds[2][512 * 40];   // [h][kv], pad 8

  const int t = threadIdx.x;
  const int lane = t & 63;
  const int w = t >> 6;
  const int l16 = lane & 15;
  const int g = lane >> 4;
  const int b = blockIdx.x;
  const int q0 = blockIdx.y * 64;
  const int qg = q0 + w * 16 + l16;          // this lane's q row
  const float kscale = 0.044194173824159216f;  // 1/sqrt(512)

  // Q fragments: B-operand, lane holds Q[q=l16-row][d = ks*32 + g*8 .. +7]
  s16x8 qf[16];
  {
    const u16* qrow = Qp + (size_t)(b * NT + qg) * NH;
#pragma unroll
    for (int ks = 0; ks < 16; ++ks)
      qf[ks] = *(const s16x8*)&qrow[ks * 32 + g * 8];
  }

  f32x4 oacc[32] = {};                 // O^T tiles: h = ht*16 + g*4 + j, q = l16
  float m_run = -1e30f, l_run = 0.f;

  const u16* kbat = Kp + (size_t)b * NT * NH;
  const u16* vbat = VpT + (size_t)b * NH * NT;

  // 2048 16B-chunks per 64KB tile pair; 256 threads x 8 chunks each.
  int4 kreg[8], vreg[8];
  // ---- stage iter 0 ----
#pragma unroll
  for (int p = 0; p < 8; ++p) {
    int c = t + 256 * p;
    kreg[p] = *(const int4*)&kbat[(size_t)(c >> 6) * NH + (c & 63) * 8];
    vreg[p] = *(const int4*)&vbat[(size_t)(c >> 2) * NT + (c & 3) * 8];
  }
#pragma unroll
  for (int p = 0; p < 8; ++p) {
    int c = t + 256 * p;
    *(int4*)&Klds[0][(c >> 6) * 520 + (c & 63) * 8] = kreg[p];
    *(int4*)&Vlds[0][(c >> 2) * 40 + (c & 3) * 8] = vreg[p];
  }
  __syncthreads();

  int pb = 0;
  for (int it = 0; it < 64; ++it) {
    // issue next-tile global loads early (hide L2 latency under compute)
    if (it < 63) {
      const int kv1 = (it + 1) * 32;
#pragma unroll
      for (int p = 0; p < 8; ++p) {
        int c = t + 256 * p;
        kreg[p] = *(const int4*)&kbat[(size_t)(kv1 + (c >> 6)) * NH + (c & 63) * 8];
        vreg[p] = *(const int4*)&vbat[(size_t)(c >> 2) * NT + kv1 + (c & 3) * 8];
      }
    }
    // ---- QK^T: S^T[32 kv][16 q] ----
    f32x4 s0 = {}, s1 = {};
#pragma unroll
    for (int ks = 0; ks < 16; ++ks) {
      s16x8 kf0 = *(const s16x8*)&Klds[pb][l16 * 520 + ks * 32 + g * 8];
      s16x8 kf1 = *(const s16x8*)&Klds[pb][(16 + l16) * 520 + ks * 32 + g * 8];
      s0 = __builtin_amdgcn_mfma_f32_16x16x32_bf16(kf0, qf[ks], s0, 0, 0, 0);
      s1 = __builtin_amdgcn_mfma_f32_16x16x32_bf16(kf1, qf[ks], s1, 0, 0, 0);
    }
    // ---- softmax (all in-register; lane's q = l16) ----
    float pv[8];
#pragma unroll
    for (int j = 0; j < 4; ++j) { pv[j] = s0[j] * kscale; pv[4 + j] = s1[j] * kscale; }
    float mx = pv[0];
#pragma unroll
    for (int j = 1; j < 8; ++j) mx = fmaxf(mx, pv[j]);
    mx = fmaxf(mx, __shfl_xor(mx, 16, 64));
    mx = fmaxf(mx, __shfl_xor(mx, 32, 64));
    if (__any(mx > m_run)) {
      const float m_new = fmaxf(m_run, mx);
      const float scale = __expf(m_run - m_new);
#pragma unroll
      for (int ht = 0; ht < 32; ++ht) {
        oacc[ht][0] *= scale; oacc[ht][1] *= scale;
        oacc[ht][2] *= scale; oacc[ht][3] *= scale;
      }
      l_run *= scale;
      m_run = m_new;
    }
    float ts = 0.f;
#pragma unroll
    for (int j = 0; j < 8; ++j) { pv[j] = __expf(pv[j] - m_run); ts += pv[j]; }
    ts += __shfl_xor(ts, 16, 64);
    ts += __shfl_xor(ts, 32, 64);
    l_run += ts;
    // ---- P^T -> B-operand fragment (8 shuffles) ----
    // lane holds P[q=l16][kv = g*4+j (tile0), 16+g*4+j (tile1)]; B-frag needs
    // P[q=l16][kv = g*8 .. g*8+7] as 4 bf16x2 words.
    u32 b0 = ((u32)f2bf(pv[1]) << 16) | f2bf(pv[0]);
    u32 b1 = ((u32)f2bf(pv[3]) << 16) | f2bf(pv[2]);
    u32 b2 = ((u32)f2bf(pv[5]) << 16) | f2bf(pv[4]);
    u32 b3 = ((u32)f2bf(pv[7]) << 16) | f2bf(pv[6]);
    const int srcA = (g & 1) * 32 + l16;
    const int srcB = srcA + 16;
    u32 x0 = (u32)__shfl((int)b0, srcA, 64);
    u32 x1 = (u32)__shfl((int)b1, srcA, 64);
    u32 x2 = (u32)__shfl((int)b2, srcA, 64);
    u32 x3 = (u32)__shfl((int)b3, srcA, 64);
    u32 y0 = (u32)__shfl((int)b0, srcB, 64);
    u32 y1 = (u32)__shfl((int)b1, srcB, 64);
    u32 y2 = (u32)__shfl((int)b2, srcB, 64);
    u32 y3 = (u32)__shfl((int)b3, srcB, 64);
    const bool hi = (lane >> 5) & 1;
    union { u32 u[4]; s16x8 v; } pf;
    pf.u[0] = hi ? x2 : x0;
    pf.u[1] = hi ? x3 : x1;
    pf.u[2] = hi ? y2 : y0;
    pf.u[3] = hi ? y3 : y1;
    // ---- PV: O^T[h][q] += V^T[h][kv] @ P^T[kv][q] ----
#pragma unroll
    for (int ht = 0; ht < 32; ++ht) {
      s16x8 vf = *(const s16x8*)&Vlds[pb][(ht * 16 + l16) * 40 + g * 8];
      oacc[ht] = __builtin_amdgcn_mfma_f32_16x16x32_bf16(vf, pf.v, oacc[ht], 0, 0, 0);
    }
    // ---- write next tile into the other buffer, single barrier ----
    if (it < 63) {
#pragma unroll
      for (int p = 0; p < 8; ++p) {
        int c = t + 256 * p;
        *(int4*)&Klds[pb ^ 1][(c >> 6) * 520 + (c & 63) * 8] = kreg[p];
        *(int4*)&Vlds[pb ^ 1][(c >> 2) * 40 + (c & 3) * 8] = vreg[p];
      }
    }
    __syncthreads();
    pb ^= 1;
  }
  // ---- epilogue: O^T / l, float4 stores (contiguous in h) ----
  const float inv = 1.f / l_run;
  float* obase = out + (size_t)(b * NT + qg) * NH;
#pragma unroll
  for (int ht = 0; ht < 32; ++ht) {
    float4 st;
    st.x = oacc[ht][0] * inv; st.y = oacc[ht][1] * inv;
    st.z = oacc[ht][2] * inv; st.w = oacc[ht][3] * inv;
    *(float4*)&obase[ht * 16 + g * 4] = st;
  }
}

extern "C" void kernel_launch(void* const* d_in, const int* in_sizes, int n_in,
                              void* d_out, int out_size, void* d_ws, size_t ws_size,
                              hipStream_t stream) {
  (void)in_sizes; (void)n_in; (void)out_size; (void)ws_size;
  const float* q  = (const float*)d_in[0];
  const float* k  = (const float*)d_in[1];
  const float* v  = (const float*)d_in[2];
  const float* Wq = (const float*)d_in[3];
  const float* bq = (const float*)d_in[4];
  const float* Wk = (const float*)d_in[5];
  const float* bk = (const float*)d_in[6];
  const float* Wv = (const float*)d_in[7];
  const float* bv = (const float*)d_in[8];
  float* out = (float*)d_out;

  u16* ws   = (u16*)d_ws;
  u16* WqT  = ws;
  u16* WkT  = WqT + (size_t)NC * NH;
  u16* WvT  = WkT + (size_t)NC * NH;
  u16* Qp   = WvT + (size_t)NC * NH;
  u16* Kp   = Qp + (size_t)NB * NT * NH;
  u16* Vp   = Kp + (size_t)NB * NT * NH;
  u16* VpT  = Vp + (size_t)NB * NT * NH;

  wt_kernel<<<dim3(16, 16), 256, 0, stream>>>(Wq, WqT);
  wt_kernel<<<dim3(16, 16), 256, 0, stream>>>(Wk, WkT);
  wt_kernel<<<dim3(16, 16), 256, 0, stream>>>(Wv, WvT);

  proj_kernel<<<dim3(4, 128), 256, 0, stream>>>(q, WqT, bq, Qp);
  proj_kernel<<<dim3(4, 128), 256, 0, stream>>>(k, WkT, bk, Kp);
  proj_kernel<<<dim3(4, 128), 256, 0, stream>>>(v, WvT, bv, Vp);

  vt_kernel<<<dim3(64, 16, NB), 256, 0, stream>>>(Vp, VpT);

  flash_kernel<<<dim3(NB, NT / 64), 256, 0, stream>>>(Qp, Kp, VpT, out);
}

// Round 4
// 332.491 us; speedup vs baseline: 1.6391x; 1.6391x over previous
//
#include <hip/hip_runtime.h>
#include <hip/hip_bf16.h>

typedef unsigned short u16;
typedef unsigned int u32;
typedef short s16x8 __attribute__((ext_vector_type(8)));
typedef float f32x4 __attribute__((ext_vector_type(4)));

#define NB 8
#define NT 2048
#define NC 512
#define NH 512

__device__ __forceinline__ u16 f2bf(float f) {
  unsigned u = __float_as_uint(f);
  u += 0x7FFFu + ((u >> 16) & 1u);   // round-to-nearest-even
  return (u16)(u >> 16);
}

// async 16B global->LDS (dest = wave-uniform base + lane*16, src per-lane)
__device__ __forceinline__ void gld16(const u16* src, u16* lds_dst) {
  __builtin_amdgcn_global_load_lds(
      (const __attribute__((address_space(1))) u32*)src,
      (__attribute__((address_space(3))) u32*)lds_dst, 16, 0, 0);
}

// ---------------- K0: W [C][H] fp32 -> WT [H][C] bf16 ----------------
__global__ __launch_bounds__(256) void wt_kernel(const float* __restrict__ W,
                                                 u16* __restrict__ WT) {
  __shared__ float tile[32][33];
  const int x = threadIdx.x & 31;
  const int y = threadIdx.x >> 5;
  const int k0 = blockIdx.x * 32, h0 = blockIdx.y * 32;
#pragma unroll
  for (int p = 0; p < 4; ++p)
    tile[y + 8 * p][x] = W[(size_t)(k0 + y + 8 * p) * NH + h0 + x];
  __syncthreads();
#pragma unroll
  for (int p = 0; p < 4; ++p)
    WT[(size_t)(h0 + y + 8 * p) * NC + k0 + x] = f2bf(tile[x][y + 8 * p]);
}

// ---------------- K1: Y = X @ W + b   (X fp32 [M][512], WT bf16 [N][K], Y bf16) ----
__global__ __launch_bounds__(256) void proj_kernel(const float* __restrict__ X,
                                                   const u16* __restrict__ WT,
                                                   const float* __restrict__ bias,
                                                   u16* __restrict__ Y) {
  __shared__ __align__(16) u16 Asub[128 * 40];
  __shared__ __align__(16) u16 Bsub[128 * 40];
  const int t = threadIdx.x;
  const int lane = t & 63;
  const int w = t >> 6;
  const int l16 = lane & 15;
  const int ko8 = (lane >> 4) * 8;
  const int m0 = blockIdx.y * 128;
  const int n0 = blockIdx.x * 128;
  const int wr = (w >> 1) * 64, wc = (w & 1) * 64;
  f32x4 acc[4][4] = {};

  for (int kt = 0; kt < 16; ++kt) {
    const int k0 = kt * 32;
#pragma unroll
    for (int p = 0; p < 4; ++p) {
      int c = t + 256 * p;
      int r = c >> 3, cc = (c & 7) * 4;
      const float4 v = *(const float4*)&X[(size_t)(m0 + r) * NC + k0 + cc];
      ushort4 bb;
      bb.x = f2bf(v.x); bb.y = f2bf(v.y); bb.z = f2bf(v.z); bb.w = f2bf(v.w);
      *(ushort4*)&Asub[r * 40 + cc] = bb;
    }
#pragma unroll
    for (int p = 0; p < 2; ++p) {
      int c = t + 256 * p;
      int r = c >> 2, cc = (c & 3) * 8;
      *(int4*)&Bsub[r * 40 + cc] = *(const int4*)&WT[(size_t)(n0 + r) * NC + k0 + cc];
    }
    __syncthreads();
    s16x8 af[4], bf[4];
#pragma unroll
    for (int i = 0; i < 4; ++i)
      af[i] = *(const s16x8*)&Asub[(wr + i * 16 + l16) * 40 + ko8];
#pragma unroll
    for (int j = 0; j < 4; ++j)
      bf[j] = *(const s16x8*)&Bsub[(wc + j * 16 + l16) * 40 + ko8];
#pragma unroll
    for (int i = 0; i < 4; ++i)
#pragma unroll
      for (int j = 0; j < 4; ++j)
        acc[i][j] = __builtin_amdgcn_mfma_f32_16x16x32_bf16(af[i], bf[j], acc[i][j], 0, 0, 0);
    __syncthreads();
  }
  const int rg = (lane >> 4) * 4;
#pragma unroll
  for (int i = 0; i < 4; ++i)
#pragma unroll
    for (int j = 0; j < 4; ++j) {
      const int col = n0 + wc + j * 16 + l16;
      const float bcol = bias[col];
#pragma unroll
      for (int jj = 0; jj < 4; ++jj) {
        const int row = m0 + wr + i * 16 + rg + jj;
        Y[(size_t)row * NH + col] = f2bf(acc[i][j][jj] + bcol);
      }
    }
}

// ---------------- K2: Vp [B][T][H] bf16 -> VpT [B][H][T] bf16 ----------------
__global__ __launch_bounds__(256) void vt_kernel(const u16* __restrict__ Vp,
                                                 u16* __restrict__ VpT) {
  __shared__ u16 tile[32][33];
  const int x = threadIdx.x & 31;
  const int y = threadIdx.x >> 5;
  const int t0 = blockIdx.x * 32, h0 = blockIdx.y * 32, b = blockIdx.z;
  const u16* src = Vp + (size_t)b * NT * NH;
  u16* dst = VpT + (size_t)b * NH * NT;
#pragma unroll
  for (int p = 0; p < 4; ++p)
    tile[y + 8 * p][x] = src[(size_t)(t0 + y + 8 * p) * NH + h0 + x];
  __syncthreads();
#pragma unroll
  for (int p = 0; p < 4; ++p)
    dst[(size_t)(h0 + y + 8 * p) * NT + t0 + x] = tile[x][y + 8 * p];
}

// ---------------- K3: flash attention ----------------
// grid (NB=8, 32), block 256 (4 waves). Each wave owns 16 q rows end-to-end.
// K/V^T staged via global_load_lds into FRAGMENT-ORDER LDS layout:
//   chunk c (16B) = frag_id*64 + lane  ->  every ds_read_b128 is 64 lanes on
//   64 consecutive chunks: conflict-free. Per-lane GLOBAL source permutation
//   realizes the layout (LDS dest stays lane-linear, as HW requires).
// K chunk (i=ks*2+kb)*64+lane holds K[kv0+kb*16+l16][ks*32+g*8 ..+7]
// V chunk ht*64+lane      holds V^T[ht*16+l16][kv0+g*8 ..+7]
// S^T = mfma(K,Q): lane q=l16, kv rows g*4+j / 16+g*4+j. Softmax in-register.
// P^T via 8 shuffles -> B-frag. O^T = mfma(V^T,P^T), float4 stores.
__global__ __launch_bounds__(256, 1) void flash_kernel(const u16* __restrict__ Qp,
                                                       const u16* __restrict__ Kp,
                                                       const u16* __restrict__ VpT,
                                                       float* __restrict__ out) {
  __shared__ __align__(16) u16 Klds[2][32 * 512];   // 32 KB each buf
  __shared__ __align__(16) u16 Vlds[2][32 * 512];   // 32 KB each buf

  const int t = threadIdx.x;
  const int lane = t & 63;
  const int w = t >> 6;
  const int l16 = lane & 15;
  const int g = lane >> 4;
  const int g8 = g * 8;
  const int b = blockIdx.x;
  const int q0 = blockIdx.y * 64;
  const int qg = q0 + w * 16 + l16;            // this lane's q row
  const float kscale = 0.044194173824159216f;  // 1/sqrt(512)

  // Q fragments: B-operand, lane holds Q[q=l16-row][d = ks*32 + g*8 .. +7]
  s16x8 qf[16];
  {
    const u16* qrow = Qp + (size_t)(b * NT + qg) * NH;
#pragma unroll
    for (int ks = 0; ks < 16; ++ks)
      qf[ks] = *(const s16x8*)&qrow[ks * 32 + g8];
  }

  f32x4 oacc[32] = {};                 // O^T tiles: h = ht*16 + g*4 + j, q = l16
  float m_run = -1e30f, l_run = 0.f;

  const u16* kbat = Kp + (size_t)b * NT * NH;
  const u16* vbat = VpT + (size_t)b * NH * NT;

  // ---- stage iter 0 into buffer 0 ----
#pragma unroll
  for (int r = 0; r < 8; ++r) {
    const int i = w * 8 + r;           // K frag id: ks = i>>1, kb = i&1
    gld16(kbat + (size_t)(((i & 1) << 4) + l16) * NH + ((i >> 1) << 5) + g8,
          &Klds[0][i * 512]);
    const int ht = i;                  // V frag id
    gld16(vbat + (size_t)(ht * 16 + l16) * NT + g8,
          &Vlds[0][ht * 512]);
  }
  __syncthreads();

  int pb = 0;
  for (int it = 0; it < 64; ++it) {
    // ---- issue next tile's async loads into the other buffer ----
    if (it < 63) {
      const int kv1 = (it + 1) * 32;
      const int nb = pb ^ 1;
#pragma unroll
      for (int r = 0; r < 8; ++r) {
        const int i = w * 8 + r;
        gld16(kbat + (size_t)(kv1 + ((i & 1) << 4) + l16) * NH + ((i >> 1) << 5) + g8,
              &Klds[nb][i * 512]);
        gld16(vbat + (size_t)(i * 16 + l16) * NT + kv1 + g8,
              &Vlds[nb][i * 512]);
      }
    }
    // ---- QK^T: S^T[32 kv][16 q] ----
    f32x4 s0 = {}, s1 = {};
#pragma unroll
    for (int ks = 0; ks < 16; ++ks) {
      s16x8 kf0 = *(const s16x8*)&Klds[pb][(ks * 2 + 0) * 512 + lane * 8];
      s16x8 kf1 = *(const s16x8*)&Klds[pb][(ks * 2 + 1) * 512 + lane * 8];
      s0 = __builtin_amdgcn_mfma_f32_16x16x32_bf16(kf0, qf[ks], s0, 0, 0, 0);
      s1 = __builtin_amdgcn_mfma_f32_16x16x32_bf16(kf1, qf[ks], s1, 0, 0, 0);
    }
    // ---- softmax (all in-register; lane's q = l16) ----
    float pv[8];
#pragma unroll
    for (int j = 0; j < 4; ++j) { pv[j] = s0[j] * kscale; pv[4 + j] = s1[j] * kscale; }
    float mx = pv[0];
#pragma unroll
    for (int j = 1; j < 8; ++j) mx = fmaxf(mx, pv[j]);
    mx = fmaxf(mx, __shfl_xor(mx, 16, 64));
    mx = fmaxf(mx, __shfl_xor(mx, 32, 64));
    if (__any(mx > m_run)) {
      const float m_new = fmaxf(m_run, mx);
      const float scale = __expf(m_run - m_new);
#pragma unroll
      for (int ht = 0; ht < 32; ++ht) {
        oacc[ht][0] *= scale; oacc[ht][1] *= scale;
        oacc[ht][2] *= scale; oacc[ht][3] *= scale;
      }
      l_run *= scale;
      m_run = m_new;
    }
    float ts = 0.f;
#pragma unroll
    for (int j = 0; j < 8; ++j) { pv[j] = __expf(pv[j] - m_run); ts += pv[j]; }
    ts += __shfl_xor(ts, 16, 64);
    ts += __shfl_xor(ts, 32, 64);
    l_run += ts;
    // ---- P^T -> B-operand fragment (8 shuffles) ----
    u32 b0 = ((u32)f2bf(pv[1]) << 16) | f2bf(pv[0]);
    u32 b1 = ((u32)f2bf(pv[3]) << 16) | f2bf(pv[2]);
    u32 b2 = ((u32)f2bf(pv[5]) << 16) | f2bf(pv[4]);
    u32 b3 = ((u32)f2bf(pv[7]) << 16) | f2bf(pv[6]);
    const int srcA = (g & 1) * 32 + l16;
    const int srcB = srcA + 16;
    u32 x0 = (u32)__shfl((int)b0, srcA, 64);
    u32 x1 = (u32)__shfl((int)b1, srcA, 64);
    u32 x2 = (u32)__shfl((int)b2, srcA, 64);
    u32 x3 = (u32)__shfl((int)b3, srcA, 64);
    u32 y0 = (u32)__shfl((int)b0, srcB, 64);
    u32 y1 = (u32)__shfl((int)b1, srcB, 64);
    u32 y2 = (u32)__shfl((int)b2, srcB, 64);
    u32 y3 = (u32)__shfl((int)b3, srcB, 64);
    const bool hi = (lane >> 5) & 1;
    union { u32 u[4]; s16x8 v; } pf;
    pf.u[0] = hi ? x2 : x0;
    pf.u[1] = hi ? x3 : x1;
    pf.u[2] = hi ? y2 : y0;
    pf.u[3] = hi ? y3 : y1;
    // ---- PV: O^T[h][q] += V^T[h][kv] @ P^T[kv][q] ----
#pragma unroll
    for (int ht = 0; ht < 32; ++ht) {
      s16x8 vf = *(const s16x8*)&Vlds[pb][ht * 512 + lane * 8];
      oacc[ht] = __builtin_amdgcn_mfma_f32_16x16x32_bf16(vf, pf.v, oacc[ht], 0, 0, 0);
    }
    // barrier: drains our async loads (compiler emits vmcnt(0) before s_barrier)
    __syncthreads();
    pb ^= 1;
  }
  // ---- epilogue: O^T / l, float4 stores (contiguous in h) ----
  const float inv = 1.f / l_run;
  float* obase = out + (size_t)(b * NT + qg) * NH;
#pragma unroll
  for (int ht = 0; ht < 32; ++ht) {
    float4 st;
    st.x = oacc[ht][0] * inv; st.y = oacc[ht][1] * inv;
    st.z = oacc[ht][2] * inv; st.w = oacc[ht][3] * inv;
    *(float4*)&obase[ht * 16 + g * 4] = st;
  }
}

extern "C" void kernel_launch(void* const* d_in, const int* in_sizes, int n_in,
                              void* d_out, int out_size, void* d_ws, size_t ws_size,
                              hipStream_t stream) {
  (void)in_sizes; (void)n_in; (void)out_size; (void)ws_size;
  const float* q  = (const float*)d_in[0];
  const float* k  = (const float*)d_in[1];
  const float* v  = (const float*)d_in[2];
  const float* Wq = (const float*)d_in[3];
  const float* bq = (const float*)d_in[4];
  const float* Wk = (const float*)d_in[5];
  const float* bk = (const float*)d_in[6];
  const float* Wv = (const float*)d_in[7];
  const float* bv = (const float*)d_in[8];
  float* out = (float*)d_out;

  u16* ws   = (u16*)d_ws;
  u16* WqT  = ws;
  u16* WkT  = WqT + (size_t)NC * NH;
  u16* WvT  = WkT + (size_t)NC * NH;
  u16* Qp   = WvT + (size_t)NC * NH;
  u16* Kp   = Qp + (size_t)NB * NT * NH;
  u16* Vp   = Kp + (size_t)NB * NT * NH;
  u16* VpT  = Vp + (size_t)NB * NT * NH;

  wt_kernel<<<dim3(16, 16), 256, 0, stream>>>(Wq, WqT);
  wt_kernel<<<dim3(16, 16), 256, 0, stream>>>(Wk, WkT);
  wt_kernel<<<dim3(16, 16), 256, 0, stream>>>(Wv, WvT);

  proj_kernel<<<dim3(4, 128), 256, 0, stream>>>(q, WqT, bq, Qp);
  proj_kernel<<<dim3(4, 128), 256, 0, stream>>>(k, WkT, bk, Kp);
  proj_kernel<<<dim3(4, 128), 256, 0, stream>>>(v, WvT, bv, Vp);

  vt_kernel<<<dim3(64, 16, NB), 256, 0, stream>>>(Vp, VpT);

  flash_kernel<<<dim3(NB, NT / 64), 256, 0, stream>>>(Qp, Kp, VpT, out);
}

// Round 5
// 309.694 us; speedup vs baseline: 1.7597x; 1.0736x over previous
//
#include <hip/hip_runtime.h>
#include <hip/hip_bf16.h>

typedef unsigned short u16;
typedef unsigned int u32;
typedef short s16x8 __attribute__((ext_vector_type(8)));
typedef short s16x4 __attribute__((ext_vector_type(4)));
typedef float f32x4 __attribute__((ext_vector_type(4)));

#define NB 8
#define NT 2048
#define NC 512
#define NH 512

#if __has_builtin(__builtin_amdgcn_mfma_f32_16x16x16_bf16)
#define MFMA_PV(va, pb, c) __builtin_amdgcn_mfma_f32_16x16x16_bf16(va, pb, c, 0, 0, 0)
#else
#define MFMA_PV(va, pb, c) __builtin_amdgcn_mfma_f32_16x16x16bf16_1k(va, pb, c, 0, 0, 0)
#endif

__device__ __forceinline__ u16 f2bf(float f) {
  unsigned u = __float_as_uint(f);
  u += 0x7FFFu + ((u >> 16) & 1u);   // round-to-nearest-even
  return (u16)(u >> 16);
}

// async 16B global->LDS (dest = wave-uniform base + lane*16, src per-lane)
__device__ __forceinline__ void gld16(const u16* src, u16* lds_dst) {
  __builtin_amdgcn_global_load_lds(
      (const __attribute__((address_space(1))) u32*)src,
      (__attribute__((address_space(3))) u32*)lds_dst, 16, 0, 0);
}

// ---------------- K0: W [C][H] fp32 -> WT [H][C] bf16 ----------------
__global__ __launch_bounds__(256) void wt_kernel(const float* __restrict__ W,
                                                 u16* __restrict__ WT) {
  __shared__ float tile[32][33];
  const int x = threadIdx.x & 31;
  const int y = threadIdx.x >> 5;
  const int k0 = blockIdx.x * 32, h0 = blockIdx.y * 32;
#pragma unroll
  for (int p = 0; p < 4; ++p)
    tile[y + 8 * p][x] = W[(size_t)(k0 + y + 8 * p) * NH + h0 + x];
  __syncthreads();
#pragma unroll
  for (int p = 0; p < 4; ++p)
    WT[(size_t)(h0 + y + 8 * p) * NC + k0 + x] = f2bf(tile[x][y + 8 * p]);
}

// ---------------- K1: Y = X @ W + b ----------------
__global__ __launch_bounds__(256) void proj_kernel(const float* __restrict__ X,
                                                   const u16* __restrict__ WT,
                                                   const float* __restrict__ bias,
                                                   u16* __restrict__ Y) {
  __shared__ __align__(16) u16 Asub[128 * 40];
  __shared__ __align__(16) u16 Bsub[128 * 40];
  const int t = threadIdx.x;
  const int lane = t & 63;
  const int w = t >> 6;
  const int l16 = lane & 15;
  const int ko8 = (lane >> 4) * 8;
  const int m0 = blockIdx.y * 128;
  const int n0 = blockIdx.x * 128;
  const int wr = (w >> 1) * 64, wc = (w & 1) * 64;
  f32x4 acc[4][4] = {};

  for (int kt = 0; kt < 16; ++kt) {
    const int k0 = kt * 32;
#pragma unroll
    for (int p = 0; p < 4; ++p) {
      int c = t + 256 * p;
      int r = c >> 3, cc = (c & 7) * 4;
      const float4 v = *(const float4*)&X[(size_t)(m0 + r) * NC + k0 + cc];
      ushort4 bb;
      bb.x = f2bf(v.x); bb.y = f2bf(v.y); bb.z = f2bf(v.z); bb.w = f2bf(v.w);
      *(ushort4*)&Asub[r * 40 + cc] = bb;
    }
#pragma unroll
    for (int p = 0; p < 2; ++p) {
      int c = t + 256 * p;
      int r = c >> 2, cc = (c & 3) * 8;
      *(int4*)&Bsub[r * 40 + cc] = *(const int4*)&WT[(size_t)(n0 + r) * NC + k0 + cc];
    }
    __syncthreads();
    s16x8 af[4], bf[4];
#pragma unroll
    for (int i = 0; i < 4; ++i)
      af[i] = *(const s16x8*)&Asub[(wr + i * 16 + l16) * 40 + ko8];
#pragma unroll
    for (int j = 0; j < 4; ++j)
      bf[j] = *(const s16x8*)&Bsub[(wc + j * 16 + l16) * 40 + ko8];
#pragma unroll
    for (int i = 0; i < 4; ++i)
#pragma unroll
      for (int j = 0; j < 4; ++j)
        acc[i][j] = __builtin_amdgcn_mfma_f32_16x16x32_bf16(af[i], bf[j], acc[i][j], 0, 0, 0);
    __syncthreads();
  }
  const int rg = (lane >> 4) * 4;
#pragma unroll
  for (int i = 0; i < 4; ++i)
#pragma unroll
    for (int j = 0; j < 4; ++j) {
      const int col = n0 + wc + j * 16 + l16;
      const float bcol = bias[col];
#pragma unroll
      for (int jj = 0; jj < 4; ++jj) {
        const int row = m0 + wr + i * 16 + rg + jj;
        Y[(size_t)row * NH + col] = f2bf(acc[i][j][jj] + bcol);
      }
    }
}

// ---------------- K2: Vp [B][T][H] bf16 -> VpT [B][H][T] bf16 ----------------
__global__ __launch_bounds__(256) void vt_kernel(const u16* __restrict__ Vp,
                                                 u16* __restrict__ VpT) {
  __shared__ u16 tile[32][33];
  const int x = threadIdx.x & 31;
  const int y = threadIdx.x >> 5;
  const int t0 = blockIdx.x * 32, h0 = blockIdx.y * 32, b = blockIdx.z;
  const u16* src = Vp + (size_t)b * NT * NH;
  u16* dst = VpT + (size_t)b * NH * NT;
#pragma unroll
  for (int p = 0; p < 4; ++p)
    tile[y + 8 * p][x] = src[(size_t)(t0 + y + 8 * p) * NH + h0 + x];
  __syncthreads();
#pragma unroll
  for (int p = 0; p < 4; ++p)
    dst[(size_t)(h0 + y + 8 * p) * NT + t0 + x] = tile[x][y + 8 * p];
}

// ---------------- K3a: flash partial (kv-split) ----------------
// grid (NB, 32, 2): z = kv half. block 256 (4 waves), 2 blocks/CU (64KB LDS).
// Each wave owns 16 q rows. KVBLK=16, double-buffered.
// K LDS: fragment-order, frag ks (u16 [ks*512 + lane*8]): K[kv0+l16][ks*32+g*8..7]
// V LDS: row-major [h][16 kv] (u16 [h*16 + kv]).
// QK: S^T[16 kv][16 q] = sum_ks mfma_16x16x32(K_frag, Q_frag); lane: q=l16, kv=g*4+j.
// Softmax in-register; pv[0..3] packs DIRECTLY into PV B-frag (16x16x16 layout
// k=g*4+j, col=l16 -- zero shuffles).
// PV: O^T[h][q] += mfma_16x16x16(V_frag, P_frag) for 32 ht tiles.
// Output: UNNORMALIZED O^T + (m,l) per row; merged by merge_kernel.
__global__ __launch_bounds__(256, 2) void flash_partial(const u16* __restrict__ Qp,
                                                        const u16* __restrict__ Kp,
                                                        const u16* __restrict__ VpT,
                                                        float* __restrict__ O0,
                                                        float* __restrict__ O1,
                                                        float* __restrict__ mlws) {
  __shared__ __align__(16) u16 Klds[2][16 * 512];   // 16 KB each
  __shared__ __align__(16) u16 Vlds[2][512 * 16];   // 16 KB each

  const int t = threadIdx.x;
  const int lane = t & 63;
  const int w = t >> 6;
  const int l16 = lane & 15;
  const int g = lane >> 4;
  const int g8 = g * 8;
  const int b = blockIdx.x;
  const int q0 = blockIdx.y * 64;
  const int half = blockIdx.z;
  const int qg = q0 + w * 16 + l16;
  const float kscale = 0.044194173824159216f;  // 1/sqrt(512)

  // Q fragments (B-operand of 16x16x32): lane holds Q[q=l16][ks*32+g*8..+7]
  s16x8 qf[16];
  {
    const u16* qrow = Qp + (size_t)(b * NT + qg) * NH;
#pragma unroll
    for (int ks = 0; ks < 16; ++ks)
      qf[ks] = *(const s16x8*)&qrow[ks * 32 + g8];
  }

  f32x4 oacc[32] = {};                 // O^T: h = ht*16 + g*4 + j, q = l16
  float m_run = -1e30f, l_run = 0.f;

  const u16* kbat = Kp + (size_t)(b * NT + half * 1024) * NH;
  const u16* vbat = VpT + (size_t)b * NH * NT + half * 1024;

  // stage tile 'it' into buffer buf (8 gld16 per wave: 4 K + 4 V)
#define STAGE(buf, it)                                                          \
  {                                                                             \
    _Pragma("unroll")                                                           \
    for (int r = 0; r < 4; ++r) {                                               \
      const int i = w * 4 + r; /* K frag id = ks */                             \
      gld16(kbat + (size_t)((it) * 16 + l16) * NH + i * 32 + g8,                \
            &Klds[buf][i * 512]);                                               \
      /* V instr i covers h rows i*32 + lane/2, kv half lane&1 */               \
      gld16(vbat + (size_t)(i * 32 + (lane >> 1)) * NT + (it) * 16 + (lane & 1) * 8, \
            &Vlds[buf][i * 512]);                                               \
    }                                                                           \
  }

  STAGE(0, 0)
  __syncthreads();

  int pb = 0;
  for (int it = 0; it < 64; ++it) {
    if (it < 63) STAGE(pb ^ 1, it + 1)
    // ---- QK^T: S^T[16 kv][16 q] ----
    f32x4 s0 = {};
#pragma unroll
    for (int ks = 0; ks < 16; ++ks) {
      s16x8 kf = *(const s16x8*)&Klds[pb][ks * 512 + lane * 8];
      s0 = __builtin_amdgcn_mfma_f32_16x16x32_bf16(kf, qf[ks], s0, 0, 0, 0);
    }
    // ---- softmax (in-register; lane's q = l16, kv = g*4+j) ----
    float pv[4];
#pragma unroll
    for (int j = 0; j < 4; ++j) pv[j] = s0[j] * kscale;
    float mx = fmaxf(fmaxf(pv[0], pv[1]), fmaxf(pv[2], pv[3]));
    mx = fmaxf(mx, __shfl_xor(mx, 16, 64));
    mx = fmaxf(mx, __shfl_xor(mx, 32, 64));
    if (__any(mx > m_run)) {
      const float m_new = fmaxf(m_run, mx);
      const float scale = __expf(m_run - m_new);
#pragma unroll
      for (int ht = 0; ht < 32; ++ht) {
        oacc[ht][0] *= scale; oacc[ht][1] *= scale;
        oacc[ht][2] *= scale; oacc[ht][3] *= scale;
      }
      l_run *= scale;
      m_run = m_new;
    }
    float ts = 0.f;
#pragma unroll
    for (int j = 0; j < 4; ++j) { pv[j] = __expf(pv[j] - m_run); ts += pv[j]; }
    ts += __shfl_xor(ts, 16, 64);
    ts += __shfl_xor(ts, 32, 64);
    l_run += ts;
    // ---- P direct pack: B-frag of 16x16x16 (k=g*4+j, col=l16) ----
    union { u32 u[2]; s16x4 v; } pf;
    pf.u[0] = ((u32)f2bf(pv[1]) << 16) | f2bf(pv[0]);
    pf.u[1] = ((u32)f2bf(pv[3]) << 16) | f2bf(pv[2]);
    // ---- PV: O^T[h][q] += V^T[h][kv] @ P^T[kv][q] ----
#pragma unroll
    for (int ht = 0; ht < 32; ++ht) {
      s16x4 vf = *(const s16x4*)&Vlds[pb][ht * 256 + l16 * 16 + g * 4];
      oacc[ht] = MFMA_PV(vf, pf.v, oacc[ht]);
    }
    __syncthreads();
    pb ^= 1;
  }
  // ---- epilogue: UNNORMALIZED O + (m,l) ----
  float* obase = (half ? O1 : O0) + (size_t)(b * NT + qg) * NH;
#pragma unroll
  for (int ht = 0; ht < 32; ++ht) {
    float4 st;
    st.x = oacc[ht][0]; st.y = oacc[ht][1];
    st.z = oacc[ht][2]; st.w = oacc[ht][3];
    *(float4*)&obase[ht * 16 + g * 4] = st;
  }
  if (g == 0) {
    const size_t row = (size_t)b * NT + qg;
    mlws[row * 4 + half * 2 + 0] = m_run;
    mlws[row * 4 + half * 2 + 1] = l_run;
  }
#undef STAGE
}

// ---------------- K3b: merge two kv-half partials ----------------
// grid (NB*NT), block 128. out = (a0*O0 + a1*O1) / (a0*l0 + a1*l1)
__global__ __launch_bounds__(128) void merge_kernel(float* __restrict__ out,
                                                    const float* __restrict__ O1,
                                                    const float* __restrict__ mlws) {
  const size_t row = blockIdx.x;
  const float m0 = mlws[row * 4 + 0], l0 = mlws[row * 4 + 1];
  const float m1 = mlws[row * 4 + 2], l1 = mlws[row * 4 + 3];
  const float m = fmaxf(m0, m1);
  const float a0 = __expf(m0 - m), a1 = __expf(m1 - m);
  const float inv = 1.f / (a0 * l0 + a1 * l1);
  const float c0 = a0 * inv, c1 = a1 * inv;
  const size_t idx = row * NH + threadIdx.x * 4;
  float4 o0 = *(const float4*)&out[idx];
  float4 o1 = *(const float4*)&O1[idx];
  float4 r;
  r.x = c0 * o0.x + c1 * o1.x;
  r.y = c0 * o0.y + c1 * o1.y;
  r.z = c0 * o0.z + c1 * o1.z;
  r.w = c0 * o0.w + c1 * o1.w;
  *(float4*)&out[idx] = r;
}

// ---------------- K3-fallback: R4 single-pass flash (if ws too small) --------
__global__ __launch_bounds__(256, 1) void flash_kernel(const u16* __restrict__ Qp,
                                                       const u16* __restrict__ Kp,
                                                       const u16* __restrict__ VpT,
                                                       float* __restrict__ out) {
  __shared__ __align__(16) u16 Klds[2][32 * 512];
  __shared__ __align__(16) u16 Vlds[2][32 * 512];

  const int t = threadIdx.x;
  const int lane = t & 63;
  const int w = t >> 6;
  const int l16 = lane & 15;
  const int g = lane >> 4;
  const int g8 = g * 8;
  const int b = blockIdx.x;
  const int q0 = blockIdx.y * 64;
  const int qg = q0 + w * 16 + l16;
  const float kscale = 0.044194173824159216f;

  s16x8 qf[16];
  {
    const u16* qrow = Qp + (size_t)(b * NT + qg) * NH;
#pragma unroll
    for (int ks = 0; ks < 16; ++ks)
      qf[ks] = *(const s16x8*)&qrow[ks * 32 + g8];
  }
  f32x4 oacc[32] = {};
  float m_run = -1e30f, l_run = 0.f;
  const u16* kbat = Kp + (size_t)b * NT * NH;
  const u16* vbat = VpT + (size_t)b * NH * NT;

#pragma unroll
  for (int r = 0; r < 8; ++r) {
    const int i = w * 8 + r;
    gld16(kbat + (size_t)(((i & 1) << 4) + l16) * NH + ((i >> 1) << 5) + g8,
          &Klds[0][i * 512]);
    gld16(vbat + (size_t)(i * 16 + l16) * NT + g8, &Vlds[0][i * 512]);
  }
  __syncthreads();

  int pb = 0;
  for (int it = 0; it < 64; ++it) {
    if (it < 63) {
      const int kv1 = (it + 1) * 32;
      const int nb = pb ^ 1;
#pragma unroll
      for (int r = 0; r < 8; ++r) {
        const int i = w * 8 + r;
        gld16(kbat + (size_t)(kv1 + ((i & 1) << 4) + l16) * NH + ((i >> 1) << 5) + g8,
              &Klds[nb][i * 512]);
        gld16(vbat + (size_t)(i * 16 + l16) * NT + kv1 + g8, &Vlds[nb][i * 512]);
      }
    }
    f32x4 s0 = {}, s1 = {};
#pragma unroll
    for (int ks = 0; ks < 16; ++ks) {
      s16x8 kf0 = *(const s16x8*)&Klds[pb][(ks * 2 + 0) * 512 + lane * 8];
      s16x8 kf1 = *(const s16x8*)&Klds[pb][(ks * 2 + 1) * 512 + lane * 8];
      s0 = __builtin_amdgcn_mfma_f32_16x16x32_bf16(kf0, qf[ks], s0, 0, 0, 0);
      s1 = __builtin_amdgcn_mfma_f32_16x16x32_bf16(kf1, qf[ks], s1, 0, 0, 0);
    }
    float pv[8];
#pragma unroll
    for (int j = 0; j < 4; ++j) { pv[j] = s0[j] * kscale; pv[4 + j] = s1[j] * kscale; }
    float mx = pv[0];
#pragma unroll
    for (int j = 1; j < 8; ++j) mx = fmaxf(mx, pv[j]);
    mx = fmaxf(mx, __shfl_xor(mx, 16, 64));
    mx = fmaxf(mx, __shfl_xor(mx, 32, 64));
    if (__any(mx > m_run)) {
      const float m_new = fmaxf(m_run, mx);
      const float scale = __expf(m_run - m_new);
#pragma unroll
      for (int ht = 0; ht < 32; ++ht) {
        oacc[ht][0] *= scale; oacc[ht][1] *= scale;
        oacc[ht][2] *= scale; oacc[ht][3] *= scale;
      }
      l_run *= scale;
      m_run = m_new;
    }
    float ts = 0.f;
#pragma unroll
    for (int j = 0; j < 8; ++j) { pv[j] = __expf(pv[j] - m_run); ts += pv[j]; }
    ts += __shfl_xor(ts, 16, 64);
    ts += __shfl_xor(ts, 32, 64);
    l_run += ts;
    u32 b0 = ((u32)f2bf(pv[1]) << 16) | f2bf(pv[0]);
    u32 b1 = ((u32)f2bf(pv[3]) << 16) | f2bf(pv[2]);
    u32 b2 = ((u32)f2bf(pv[5]) << 16) | f2bf(pv[4]);
    u32 b3 = ((u32)f2bf(pv[7]) << 16) | f2bf(pv[6]);
    const int srcA = (g & 1) * 32 + l16;
    const int srcB = srcA + 16;
    u32 x0 = (u32)__shfl((int)b0, srcA, 64);
    u32 x1 = (u32)__shfl((int)b1, srcA, 64);
    u32 x2 = (u32)__shfl((int)b2, srcA, 64);
    u32 x3 = (u32)__shfl((int)b3, srcA, 64);
    u32 y0 = (u32)__shfl((int)b0, srcB, 64);
    u32 y1 = (u32)__shfl((int)b1, srcB, 64);
    u32 y2 = (u32)__shfl((int)b2, srcB, 64);
    u32 y3 = (u32)__shfl((int)b3, srcB, 64);
    const bool hi = (lane >> 5) & 1;
    union { u32 u[4]; s16x8 v; } pf;
    pf.u[0] = hi ? x2 : x0;
    pf.u[1] = hi ? x3 : x1;
    pf.u[2] = hi ? y2 : y0;
    pf.u[3] = hi ? y3 : y1;
#pragma unroll
    for (int ht = 0; ht < 32; ++ht) {
      s16x8 vf = *(const s16x8*)&Vlds[pb][ht * 512 + lane * 8];
      oacc[ht] = __builtin_amdgcn_mfma_f32_16x16x32_bf16(vf, pf.v, oacc[ht], 0, 0, 0);
    }
    __syncthreads();
    pb ^= 1;
  }
  const float inv = 1.f / l_run;
  float* obase = out + (size_t)(b * NT + qg) * NH;
#pragma unroll
  for (int ht = 0; ht < 32; ++ht) {
    float4 st;
    st.x = oacc[ht][0] * inv; st.y = oacc[ht][1] * inv;
    st.z = oacc[ht][2] * inv; st.w = oacc[ht][3] * inv;
    *(float4*)&obase[ht * 16 + g * 4] = st;
  }
}

extern "C" void kernel_launch(void* const* d_in, const int* in_sizes, int n_in,
                              void* d_out, int out_size, void* d_ws, size_t ws_size,
                              hipStream_t stream) {
  (void)in_sizes; (void)n_in; (void)out_size;
  const float* q  = (const float*)d_in[0];
  const float* k  = (const float*)d_in[1];
  const float* v  = (const float*)d_in[2];
  const float* Wq = (const float*)d_in[3];
  const float* bq = (const float*)d_in[4];
  const float* Wk = (const float*)d_in[5];
  const float* bk = (const float*)d_in[6];
  const float* Wv = (const float*)d_in[7];
  const float* bv = (const float*)d_in[8];
  float* out = (float*)d_out;

  u16* ws   = (u16*)d_ws;
  u16* WqT  = ws;
  u16* WkT  = WqT + (size_t)NC * NH;
  u16* WvT  = WkT + (size_t)NC * NH;
  u16* Qp   = WvT + (size_t)NC * NH;
  u16* Kp   = Qp + (size_t)NB * NT * NH;
  u16* Vp   = Kp + (size_t)NB * NT * NH;
  u16* VpT  = Vp + (size_t)NB * NT * NH;
  u16* endb = VpT + (size_t)NB * NT * NH;
  // extra (kv-split path): O1 partial (f32, 32MB) + mlws (f32, 256KB)
  float* O1   = (float*)endb;
  float* mlws = O1 + (size_t)NB * NT * NH;
  const size_t need = (size_t)((char*)(mlws + (size_t)NB * NT * 4) - (char*)d_ws);

  wt_kernel<<<dim3(16, 16), 256, 0, stream>>>(Wq, WqT);
  wt_kernel<<<dim3(16, 16), 256, 0, stream>>>(Wk, WkT);
  wt_kernel<<<dim3(16, 16), 256, 0, stream>>>(Wv, WvT);

  proj_kernel<<<dim3(4, 128), 256, 0, stream>>>(q, WqT, bq, Qp);
  proj_kernel<<<dim3(4, 128), 256, 0, stream>>>(k, WkT, bk, Kp);
  proj_kernel<<<dim3(4, 128), 256, 0, stream>>>(v, WvT, bv, Vp);

  vt_kernel<<<dim3(64, 16, NB), 256, 0, stream>>>(Vp, VpT);

  if (ws_size >= need) {
    flash_partial<<<dim3(NB, NT / 64, 2), 256, 0, stream>>>(Qp, Kp, VpT, out, O1, mlws);
    merge_kernel<<<dim3(NB * NT), 128, 0, stream>>>(out, O1, mlws);
  } else {
    flash_kernel<<<dim3(NB, NT / 64), 256, 0, stream>>>(Qp, Kp, VpT, out);
  }
}